// Round 6
// baseline (391.599 us; speedup 1.0000x reference)
//
#include <hip/hip_runtime.h>
#include <hip/hip_cooperative_groups.h>
#include <cstdint>
#include <cstddef>

namespace cg = cooperative_groups;

#define NB 64
#define NA 4096
#define ND 512
#define NGROUPS (NB * NA / 4)   // 65536 groups of 4 actions

// ---------- JAX threefry2x32, key = jax.random.key(42) -> (0, 42) ----------
// Partitionable path: per flat element n, pair = (0, n); sub-64-bit widths
// XOR-fold the two output words: bits = x0_final ^ x1_final.  (verified R3)
__device__ __forceinline__ unsigned rotl32(unsigned x, int d){ return (x << d) | (x >> (32 - d)); }

__device__ unsigned threefry_bits(unsigned n){
  const unsigned ks0 = 0u;
  const unsigned ks1 = 42u;
  const unsigned ks2 = 0x1BD11BDAu ^ ks0 ^ ks1;
  unsigned x0 = 0u;
  unsigned x1 = n;
  x0 += ks0; x1 += ks1;
  const int r0[4] = {13, 15, 26, 6};
  const int r1[4] = {17, 29, 16, 24};
  #pragma unroll
  for (int j = 0; j < 4; j++){ x0 += x1; x1 = rotl32(x1, r0[j]); x1 ^= x0; }
  x0 += ks1; x1 += ks2 + 1u;
  #pragma unroll
  for (int j = 0; j < 4; j++){ x0 += x1; x1 = rotl32(x1, r1[j]); x1 ^= x0; }
  x0 += ks2; x1 += ks0 + 2u;
  #pragma unroll
  for (int j = 0; j < 4; j++){ x0 += x1; x1 = rotl32(x1, r0[j]); x1 ^= x0; }
  x0 += ks0; x1 += ks1 + 3u;
  #pragma unroll
  for (int j = 0; j < 4; j++){ x0 += x1; x1 = rotl32(x1, r1[j]); x1 ^= x0; }
  x0 += ks1; x1 += ks2 + 4u;
  #pragma unroll
  for (int j = 0; j < 4; j++){ x0 += x1; x1 = rotl32(x1, r0[j]); x1 ^= x0; }
  x0 += ks2; x1 += ks0 + 5u;
  return x0 ^ x1;
}

// ---------- fused: logits+min (grid-stride) | grid.sync | per-row top-5+sample ----------
__global__ __launch_bounds__(256, 8)
void fused_kernel(const float* __restrict__ s,
                  const float* __restrict__ ae,
                  const void*  __restrict__ maskp,
                  const unsigned* __restrict__ alpha_raw,
                  float* __restrict__ out,
                  float* __restrict__ minbuf){
  __shared__ float smin[4];
  __shared__ float row[NA];
  __shared__ float su[4];
  __shared__ float rv[4]; __shared__ int ri[4];
  __shared__ float selv[5]; __shared__ int seli[5];
  __shared__ int s_mflag;
  __shared__ float s_fill;

  const int bid  = blockIdx.x;
  const int nblk = gridDim.x;
  const int t    = threadIdx.x;
  const int wave = t >> 6;
  const int lane = t & 63;
  float* logits = out + NB;

  // ===== phase 1: dense-front grid-stride over action groups, no sync in loop =====
  float wmin = INFINITY;
  for (int g = bid; g < NGROUPS; g += nblk){
    int b = g >> 10;
    int a = ((g & 1023) << 2) | wave;
    const float* ar = ae + ((size_t)b * NA + a) * ND;
    const float* sr = s + b * ND;
    float4 a0 = *(const float4*)(ar + lane * 4);
    float4 a1 = *(const float4*)(ar + 256 + lane * 4);
    float4 s0 = *(const float4*)(sr + lane * 4);
    float4 s1 = *(const float4*)(sr + 256 + lane * 4);
    float p = a0.x*s0.x + a0.y*s0.y + a0.z*s0.z + a0.w*s0.w
            + a1.x*s1.x + a1.y*s1.y + a1.z*s1.z + a1.w*s1.w;
    #pragma unroll
    for (int off = 32; off > 0; off >>= 1) p += __shfl_xor(p, off, 64);
    wmin = fminf(wmin, p);
    if (lane == 0) logits[(size_t)b * NA + a] = p;
  }
  if (lane == 0) smin[wave] = wmin;
  __syncthreads();
  if (t == 0)
    minbuf[bid] = fminf(fminf(smin[0], smin[1]), fminf(smin[2], smin[3]));

  cg::this_grid().sync();

  // ===== phase 2: blocks 0..63 do per-row work =====
  if (bid >= NB) return;
  const int b = bid;
  float* lrow = logits + (size_t)b * NA;
  const unsigned char* m8  = (const unsigned char*)maskp;
  const unsigned*      m32 = (const unsigned*)maskp;

  // -- mask dtype detect: first 4096 u32 words (16 KB, in-bounds either way)
  if (t == 0) s_mflag = 1;
  __syncthreads();
  for (int i = t; i < 4096; i += 256)
    if (m32[i] > 1u) s_mflag = 0;          // benign race, only 0 written

  // -- fold per-block mins
  float e = INFINITY;
  for (int i = t; i < nblk; i += 256) e = fminf(e, minbuf[i]);
  #pragma unroll
  for (int off = 32; off > 0; off >>= 1) e = fminf(e, __shfl_xor(e, off, 64));
  if ((t & 63) == 0) su[t >> 6] = e;
  __syncthreads();
  if (t == 0)
    s_fill = fminf(fminf(su[0], su[1]), fminf(su[2], su[3])) - 1.0f;
  __syncthreads();
  int   mflag = s_mflag;
  float fill  = s_fill;

  // -- mask-fill row (in place: masked logits are the returned logits)
  for (int a = t; a < NA; a += 256){
    int idx = b * NA + a;
    bool av = mflag ? (m32[idx] != 0u) : (m8[idx] != 0);
    float v = lrow[a];
    float mv = av ? v : fill;
    row[a]  = mv;
    lrow[a] = mv;
  }
  __syncthreads();

  // -- top-5 (5 passes, smallest-index tie-break like jax.lax.top_k)
  for (int k = 0; k < 5; k++){
    float bv = -INFINITY; int bi = 0x7FFFFFFF;
    for (int a = t; a < NA; a += 256){
      float v = row[a];
      if (v > bv){ bv = v; bi = a; }
    }
    #pragma unroll
    for (int off = 32; off > 0; off >>= 1){
      float ov = __shfl_xor(bv, off, 64);
      int   oi = __shfl_xor(bi, off, 64);
      if (ov > bv || (ov == bv && oi < bi)){ bv = ov; bi = oi; }
    }
    if ((t & 63) == 0){ rv[t >> 6] = bv; ri[t >> 6] = bi; }
    __syncthreads();
    if (t == 0){
      float fv = rv[0]; int fi = ri[0];
      for (int w = 1; w < 4; w++)
        if (rv[w] > fv || (rv[w] == fv && ri[w] < fi)){ fv = rv[w]; fi = ri[w]; }
      selv[k] = fv; seli[k] = fi;
      row[fi] = -INFINITY;
    }
    __syncthreads();
  }

  // -- gumbel-argmax sample over keep = available & top5
  if (t == 0){
    unsigned ab = *alpha_raw;   // int scalar or float bits — disambiguate
    float alpha = (ab < 0x00800000u) ? (float)(int)ab : __uint_as_float(ab);
    float best = -INFINITY; int ba = 0;
    for (int k = 0; k < 5; k++){
      int idx  = seli[k];
      int gidx = b * NA + idx;
      bool av = mflag ? (m32[gidx] != 0u) : (m8[gidx] != 0);
      if (!av) continue;
      unsigned bits = threefry_bits((unsigned)gidx);
      float f = __uint_as_float((bits >> 9) | 0x3F800000u) - 1.0f;  // [0,1)
      const float tiny = 1.17549435e-38f;
      float u = fmaxf(tiny, f + tiny);
      float g = -logf(-logf(u));
      // argmax(log softmax_renorm) + g  ==  argmax(l/alpha + g) over keep set
      float sc = selv[k] / alpha + g;
      if (sc > best){ best = sc; ba = idx; }
    }
    out[b] = (float)ba;
  }
}

extern "C" void kernel_launch(void* const* d_in, const int* in_sizes, int n_in,
                              void* d_out, int out_size, void* d_ws, size_t ws_size,
                              hipStream_t stream){
  const float*    s     = (const float*)d_in[0];
  const float*    ae    = (const float*)d_in[1];
  const void*     mask  = d_in[2];
  const unsigned* alpha = (const unsigned*)d_in[3];
  float* out = (float*)d_out;
  float* ws  = (float*)d_ws;

  int occ = 0;
  (void)hipOccupancyMaxActiveBlocksPerMultiprocessor(&occ, (const void*)fused_kernel, 256, 0);
  if (occ < 1) occ = 1;
  if (occ > 8) occ = 8;
  int grid = 256 * occ;           // co-resident by construction; >= 256 >= NB

  void* args[] = {(void*)&s, (void*)&ae, (void*)&mask, (void*)&alpha,
                  (void*)&out, (void*)&ws};
  (void)hipLaunchCooperativeKernel((const void*)fused_kernel, dim3(grid), dim3(256),
                                   args, 0, stream);
}

// Round 7
// 134.515 us; speedup vs baseline: 2.9112x; 2.9112x over previous
//
#include <hip/hip_runtime.h>
#include <cstdint>
#include <cstddef>

#define NB 64
#define NA 4096
#define ND 512
#define NGROUPS (NB * NA / 4)   // 65536 groups of 4 actions (one per wave)
#define DOT_GRID 2048           // 8 blocks/CU x 256 CUs

// ---------- JAX threefry2x32, key = jax.random.key(42) -> (0, 42) ----------
// Partitionable path: per flat element n, pair = (0, n); sub-64-bit widths
// XOR-fold the two output words: bits = x0_final ^ x1_final.  (verified R3)
__device__ __forceinline__ unsigned rotl32(unsigned x, int d){ return (x << d) | (x >> (32 - d)); }

__device__ unsigned threefry_bits(unsigned n){
  const unsigned ks0 = 0u;
  const unsigned ks1 = 42u;
  const unsigned ks2 = 0x1BD11BDAu ^ ks0 ^ ks1;
  unsigned x0 = 0u;
  unsigned x1 = n;
  x0 += ks0; x1 += ks1;
  const int r0[4] = {13, 15, 26, 6};
  const int r1[4] = {17, 29, 16, 24};
  #pragma unroll
  for (int j = 0; j < 4; j++){ x0 += x1; x1 = rotl32(x1, r0[j]); x1 ^= x0; }
  x0 += ks1; x1 += ks2 + 1u;
  #pragma unroll
  for (int j = 0; j < 4; j++){ x0 += x1; x1 = rotl32(x1, r1[j]); x1 ^= x0; }
  x0 += ks2; x1 += ks0 + 2u;
  #pragma unroll
  for (int j = 0; j < 4; j++){ x0 += x1; x1 = rotl32(x1, r0[j]); x1 ^= x0; }
  x0 += ks0; x1 += ks1 + 3u;
  #pragma unroll
  for (int j = 0; j < 4; j++){ x0 += x1; x1 = rotl32(x1, r1[j]); x1 ^= x0; }
  x0 += ks1; x1 += ks2 + 4u;
  #pragma unroll
  for (int j = 0; j < 4; j++){ x0 += x1; x1 = rotl32(x1, r0[j]); x1 ^= x0; }
  x0 += ks2; x1 += ks0 + 5u;
  return x0 ^ x1;
}

// ---------- logits + per-block min : grid-stride, 1 action per wave ----------
__global__ __launch_bounds__(256, 8)
void dot_kernel(const float* __restrict__ s,
                const float* __restrict__ ae,
                float* __restrict__ logits,
                float* __restrict__ minbuf){
  __shared__ float smin[4];
  const int bid  = blockIdx.x;
  const int wave = threadIdx.x >> 6;
  const int lane = threadIdx.x & 63;
  float wmin = INFINITY;
  for (int g = bid; g < NGROUPS; g += DOT_GRID){
    int b = g >> 10;
    int a = ((g & 1023) << 2) | wave;
    const float* ar = ae + ((size_t)b * NA + a) * ND;
    const float* sr = s + b * ND;
    float4 a0 = *(const float4*)(ar + lane * 4);
    float4 a1 = *(const float4*)(ar + 256 + lane * 4);
    float4 s0 = *(const float4*)(sr + lane * 4);
    float4 s1 = *(const float4*)(sr + 256 + lane * 4);
    float p = a0.x*s0.x + a0.y*s0.y + a0.z*s0.z + a0.w*s0.w
            + a1.x*s1.x + a1.y*s1.y + a1.z*s1.z + a1.w*s1.w;
    #pragma unroll
    for (int off = 32; off > 0; off >>= 1) p += __shfl_xor(p, off, 64);
    wmin = fminf(wmin, p);
    if (lane == 0) logits[(size_t)b * NA + a] = p;
  }
  if (lane == 0) smin[wave] = wmin;
  __syncthreads();
  if (threadIdx.x == 0)
    minbuf[bid] = fminf(fminf(smin[0], smin[1]), fminf(smin[2], smin[3]));
}

// ---------- per row: detect mask dtype, fold min, mask-fill, top-5, sample ----------
__global__ __launch_bounds__(256) void row_kernel(float* __restrict__ out,
                                                  const void* __restrict__ maskp,
                                                  const float* __restrict__ minbuf,
                                                  const unsigned* __restrict__ alpha_raw){
  __shared__ float row[NA];
  __shared__ float su[4];
  __shared__ float rv[4]; __shared__ int ri[4];
  __shared__ float selv[5]; __shared__ int seli[5];
  __shared__ int s_mflag;
  __shared__ float s_fill;
  int b = blockIdx.x;
  int t = threadIdx.x;
  float* lrow = out + NB + (size_t)b * NA;
  const unsigned char* m8  = (const unsigned char*)maskp;
  const unsigned*      m32 = (const unsigned*)maskp;

  // -- mask dtype detect: first 4096 u32 words (16 KB, in-bounds either way)
  if (t == 0) s_mflag = 1;
  __syncthreads();
  for (int i = t; i < 4096; i += 256)
    if (m32[i] > 1u) s_mflag = 0;          // benign race, only 0 written

  // -- fold per-block mins (8 per thread)
  float e = INFINITY;
  for (int i = t; i < DOT_GRID; i += 256) e = fminf(e, minbuf[i]);
  #pragma unroll
  for (int off = 32; off > 0; off >>= 1) e = fminf(e, __shfl_xor(e, off, 64));
  if ((t & 63) == 0) su[t >> 6] = e;
  __syncthreads();
  if (t == 0)
    s_fill = fminf(fminf(su[0], su[1]), fminf(su[2], su[3])) - 1.0f;
  __syncthreads();
  int   mflag = s_mflag;
  float fill  = s_fill;

  // -- mask-fill row (in place: masked logits are the returned logits)
  for (int a = t; a < NA; a += 256){
    int idx = b * NA + a;
    bool av = mflag ? (m32[idx] != 0u) : (m8[idx] != 0);
    float v = lrow[a];
    float mv = av ? v : fill;
    row[a]  = mv;
    lrow[a] = mv;
  }
  __syncthreads();

  // -- top-5 (5 passes, smallest-index tie-break like jax.lax.top_k)
  for (int k = 0; k < 5; k++){
    float bv = -INFINITY; int bi = 0x7FFFFFFF;
    for (int a = t; a < NA; a += 256){
      float v = row[a];
      if (v > bv){ bv = v; bi = a; }
    }
    #pragma unroll
    for (int off = 32; off > 0; off >>= 1){
      float ov = __shfl_xor(bv, off, 64);
      int   oi = __shfl_xor(bi, off, 64);
      if (ov > bv || (ov == bv && oi < bi)){ bv = ov; bi = oi; }
    }
    if ((t & 63) == 0){ rv[t >> 6] = bv; ri[t >> 6] = bi; }
    __syncthreads();
    if (t == 0){
      float fv = rv[0]; int fi = ri[0];
      for (int w = 1; w < 4; w++)
        if (rv[w] > fv || (rv[w] == fv && ri[w] < fi)){ fv = rv[w]; fi = ri[w]; }
      selv[k] = fv; seli[k] = fi;
      row[fi] = -INFINITY;
    }
    __syncthreads();
  }

  // -- gumbel-argmax sample over keep = available & top5
  if (t == 0){
    unsigned ab = *alpha_raw;   // int scalar or float bits — disambiguate
    float alpha = (ab < 0x00800000u) ? (float)(int)ab : __uint_as_float(ab);
    float best = -INFINITY; int ba = 0;
    for (int k = 0; k < 5; k++){
      int idx  = seli[k];
      int gidx = b * NA + idx;
      bool av = mflag ? (m32[gidx] != 0u) : (m8[gidx] != 0);
      if (!av) continue;
      unsigned bits = threefry_bits((unsigned)gidx);
      float f = __uint_as_float((bits >> 9) | 0x3F800000u) - 1.0f;  // [0,1)
      const float tiny = 1.17549435e-38f;
      float u = fmaxf(tiny, f + tiny);
      float g = -logf(-logf(u));
      // argmax(log softmax_renorm) + g  ==  argmax(l/alpha + g) over keep set
      float sc = selv[k] / alpha + g;
      if (sc > best){ best = sc; ba = idx; }
    }
    out[b] = (float)ba;
  }
}

extern "C" void kernel_launch(void* const* d_in, const int* in_sizes, int n_in,
                              void* d_out, int out_size, void* d_ws, size_t ws_size,
                              hipStream_t stream){
  const float*    s     = (const float*)d_in[0];
  const float*    ae    = (const float*)d_in[1];
  const void*     mask  = d_in[2];
  const unsigned* alpha = (const unsigned*)d_in[3];
  float* out = (float*)d_out;
  float* ws  = (float*)d_ws;

  hipLaunchKernelGGL(dot_kernel, dim3(DOT_GRID), dim3(256), 0, stream, s, ae, out + NB, ws);
  hipLaunchKernelGGL(row_kernel, dim3(NB),       dim3(256), 0, stream, out, mask, ws, alpha);
}

// Round 8
// 109.751 us; speedup vs baseline: 3.5681x; 1.2256x over previous
//
#include <hip/hip_runtime.h>
#include <cstdint>
#include <cstddef>

#define NB 64
#define NA 4096
#define ND 512

typedef float f32x4 __attribute__((ext_vector_type(4)));

// ---------- float <-> order-preserving unsigned encoding (for atomicMin) ----------
__device__ __forceinline__ unsigned enc_f(float f){
  unsigned b = __float_as_uint(f);
  return (b & 0x80000000u) ? ~b : (b | 0x80000000u);
}
__device__ __forceinline__ float dec_f(unsigned e){
  unsigned b = (e & 0x80000000u) ? (e ^ 0x80000000u) : ~e;
  return __uint_as_float(b);
}

// ---------- JAX threefry2x32, key = jax.random.key(42) -> (0, 42) ----------
// Partitionable path: per flat element n, pair = (0, n); sub-64-bit widths
// XOR-fold the two output words: bits = x0_final ^ x1_final.  (verified R3)
__device__ __forceinline__ unsigned rotl32(unsigned x, int d){ return (x << d) | (x >> (32 - d)); }

__device__ unsigned threefry_bits(unsigned n){
  const unsigned ks0 = 0u;
  const unsigned ks1 = 42u;
  const unsigned ks2 = 0x1BD11BDAu ^ ks0 ^ ks1;
  unsigned x0 = 0u;
  unsigned x1 = n;
  x0 += ks0; x1 += ks1;
  const int r0[4] = {13, 15, 26, 6};
  const int r1[4] = {17, 29, 16, 24};
  #pragma unroll
  for (int j = 0; j < 4; j++){ x0 += x1; x1 = rotl32(x1, r0[j]); x1 ^= x0; }
  x0 += ks1; x1 += ks2 + 1u;
  #pragma unroll
  for (int j = 0; j < 4; j++){ x0 += x1; x1 = rotl32(x1, r1[j]); x1 ^= x0; }
  x0 += ks2; x1 += ks0 + 2u;
  #pragma unroll
  for (int j = 0; j < 4; j++){ x0 += x1; x1 = rotl32(x1, r0[j]); x1 ^= x0; }
  x0 += ks0; x1 += ks1 + 3u;
  #pragma unroll
  for (int j = 0; j < 4; j++){ x0 += x1; x1 = rotl32(x1, r1[j]); x1 ^= x0; }
  x0 += ks1; x1 += ks2 + 4u;
  #pragma unroll
  for (int j = 0; j < 4; j++){ x0 += x1; x1 = rotl32(x1, r0[j]); x1 ^= x0; }
  x0 += ks2; x1 += ks0 + 5u;
  return x0 ^ x1;
}

// ---------- init: 256 hierarchical min slots (stride 16 words = 64 B) ----------
__global__ void init_ws(unsigned* ws){ ws[threadIdx.x * 16] = 0xFFFFFFFFu; }

// ---------- logits + hierarchical global-min : one wave per action ----------
__global__ __launch_bounds__(256) void dot_kernel(const float* __restrict__ s,
                                                  const float* __restrict__ ae,
                                                  float* __restrict__ logits,
                                                  unsigned* __restrict__ minw){
  __shared__ unsigned sm[4];
  int wave = threadIdx.x >> 6;
  int lane = threadIdx.x & 63;
  int blk  = blockIdx.x;          // 65536 blocks: b = blk>>10, 4 actions per block
  int b = blk >> 10;
  int a = ((blk & 1023) << 2) | wave;
  const float* ar = ae + (size_t)(b * NA + a) * ND;
  const float* sr = s + b * ND;
  // a_embeds: zero-reuse stream -> nontemporal (no L2/L3 allocation)
  f32x4 a0 = __builtin_nontemporal_load((const f32x4*)(ar + lane * 4));
  f32x4 a1 = __builtin_nontemporal_load((const f32x4*)(ar + 256 + lane * 4));
  // s_embed: reused by all blocks of the same row -> cached load
  f32x4 s0 = *(const f32x4*)(sr + lane * 4);
  f32x4 s1 = *(const f32x4*)(sr + 256 + lane * 4);
  float p = a0.x*s0.x + a0.y*s0.y + a0.z*s0.z + a0.w*s0.w
          + a1.x*s1.x + a1.y*s1.y + a1.z*s1.z + a1.w*s1.w;
  #pragma unroll
  for (int off = 32; off > 0; off >>= 1) p += __shfl_xor(p, off, 64);
  if (lane == 0){
    logits[(size_t)b * NA + a] = p;
    sm[wave] = enc_f(p);
  }
  __syncthreads();
  if (threadIdx.x == 0){
    unsigned m01 = sm[0] < sm[1] ? sm[0] : sm[1];
    unsigned m23 = sm[2] < sm[3] ? sm[2] : sm[3];
    unsigned m   = m01 < m23 ? m01 : m23;
    atomicMin(minw + (blk & 255) * 16, m);   // 256 atomics per slot
  }
}

// ---------- per row: detect mask dtype, fold min, mask-fill, top-5, sample ----------
__global__ __launch_bounds__(256) void row_kernel(float* __restrict__ out,
                                                  const void* __restrict__ maskp,
                                                  const unsigned* __restrict__ ws,
                                                  const unsigned* __restrict__ alpha_raw){
  __shared__ float row[NA];
  __shared__ unsigned su[4];
  __shared__ float rv[4]; __shared__ int ri[4];
  __shared__ float selv[5]; __shared__ int seli[5];
  __shared__ int s_mflag;
  __shared__ float s_fill;
  int b = blockIdx.x;
  int t = threadIdx.x;
  float* lrow = out + NB + (size_t)b * NA;
  const unsigned char* m8  = (const unsigned char*)maskp;
  const unsigned*      m32 = (const unsigned*)maskp;

  // -- mask dtype detect: first 4096 u32 words (16 KB, in-bounds either way).
  if (t == 0) s_mflag = 1;
  __syncthreads();
  for (int i = t; i < 4096; i += 256)
    if (m32[i] > 1u) s_mflag = 0;          // benign race, only 0 written

  // -- fold 256 hierarchical min slots (one per thread)
  unsigned e = ws[t * 16];
  #pragma unroll
  for (int off = 32; off > 0; off >>= 1){
    unsigned o = __shfl_xor(e, off, 64);
    e = o < e ? o : e;
  }
  if ((t & 63) == 0) su[t >> 6] = e;
  __syncthreads();
  if (t == 0){
    unsigned r01 = su[0] < su[1] ? su[0] : su[1];
    unsigned r23 = su[2] < su[3] ? su[2] : su[3];
    unsigned r   = r01 < r23 ? r01 : r23;
    s_fill = dec_f(r) - 1.0f;
  }
  __syncthreads();
  int   mflag = s_mflag;
  float fill  = s_fill;

  // -- mask-fill row (in place: masked logits are the returned logits)
  for (int a = t; a < NA; a += 256){
    int idx = b * NA + a;
    bool av = mflag ? (m32[idx] != 0u) : (m8[idx] != 0);
    float v = lrow[a];
    float mv = av ? v : fill;
    row[a]  = mv;
    lrow[a] = mv;
  }
  __syncthreads();

  // -- top-5 (5 passes, smallest-index tie-break like jax.lax.top_k)
  for (int k = 0; k < 5; k++){
    float bv = -INFINITY; int bi = 0x7FFFFFFF;
    for (int a = t; a < NA; a += 256){
      float v = row[a];
      if (v > bv){ bv = v; bi = a; }
    }
    #pragma unroll
    for (int off = 32; off > 0; off >>= 1){
      float ov = __shfl_xor(bv, off, 64);
      int   oi = __shfl_xor(bi, off, 64);
      if (ov > bv || (ov == bv && oi < bi)){ bv = ov; bi = oi; }
    }
    if ((t & 63) == 0){ rv[t >> 6] = bv; ri[t >> 6] = bi; }
    __syncthreads();
    if (t == 0){
      float fv = rv[0]; int fi = ri[0];
      for (int w = 1; w < 4; w++)
        if (rv[w] > fv || (rv[w] == fv && ri[w] < fi)){ fv = rv[w]; fi = ri[w]; }
      selv[k] = fv; seli[k] = fi;
      row[fi] = -INFINITY;
    }
    __syncthreads();
  }

  // -- gumbel-argmax sample over keep = available & top5
  if (t == 0){
    unsigned ab = *alpha_raw;   // int scalar or float bits — disambiguate
    float alpha = (ab < 0x00800000u) ? (float)(int)ab : __uint_as_float(ab);
    float best = -INFINITY; int ba = 0;
    for (int k = 0; k < 5; k++){
      int idx  = seli[k];
      int gidx = b * NA + idx;
      bool av = mflag ? (m32[gidx] != 0u) : (m8[gidx] != 0);
      if (!av) continue;
      unsigned bits = threefry_bits((unsigned)gidx);
      float f = __uint_as_float((bits >> 9) | 0x3F800000u) - 1.0f;  // [0,1)
      const float tiny = 1.17549435e-38f;
      float u = fmaxf(tiny, f + tiny);
      float g = -logf(-logf(u));
      // argmax(log softmax_renorm) + g  ==  argmax(l/alpha + g) over keep set
      float sc = selv[k] / alpha + g;
      if (sc > best){ best = sc; ba = idx; }
    }
    out[b] = (float)ba;
  }
}

extern "C" void kernel_launch(void* const* d_in, const int* in_sizes, int n_in,
                              void* d_out, int out_size, void* d_ws, size_t ws_size,
                              hipStream_t stream){
  const float*    s     = (const float*)d_in[0];
  const float*    ae    = (const float*)d_in[1];
  const void*     mask  = d_in[2];
  const unsigned* alpha = (const unsigned*)d_in[3];
  float*    out = (float*)d_out;
  unsigned* ws  = (unsigned*)d_ws;

  hipLaunchKernelGGL(init_ws,    dim3(1),           dim3(256), 0, stream, ws);
  hipLaunchKernelGGL(dot_kernel, dim3(NB * NA / 4), dim3(256), 0, stream, s, ae, out + NB, ws);
  hipLaunchKernelGGL(row_kernel, dim3(NB),          dim3(256), 0, stream, out, mask, ws, alpha);
}